// Round 8
// baseline (182.246 us; speedup 1.0000x reference)
//
#include <hip/hip_runtime.h>
#include <hip/hip_bf16.h>
#include <math.h>

#define BB 2
#define LL 2048
#define EE 512
#define HH 8
#define DD 64
#define MM (BB * LL)   // 4096
#define LW (LL / 64)   // 32 k-tiles of 64
#define NSP 2          // KV splits
#define NT (LW / NSP)  // 16 kv-tiles per split

typedef short bf16x8 __attribute__((ext_vector_type(8)));   // 8 bf16 = 4 VGPRs
typedef float f32x4 __attribute__((ext_vector_type(4)));
typedef float f32x16 __attribute__((ext_vector_type(16)));

#define MFMA16(a, b, c) __builtin_amdgcn_mfma_f32_16x16x32_bf16((a), (b), (c), 0, 0, 0)
#define MFMA32(a, b, c) __builtin_amdgcn_mfma_f32_32x32x16_bf16((a), (b), (c), 0, 0, 0)

#if __has_builtin(__builtin_amdgcn_exp2f)
#define EXP2(x) __builtin_amdgcn_exp2f(x)
#else
#define EXP2(x) exp2f(x)
#endif

// q-scale with log2(e) folded: (1/sqrt(512)) * log2(e)
#define QSCALE 0.0637587146f

// async global->LDS, 16B per lane; LDS dest = wave-uniform base + lane*16B
__device__ __forceinline__ void gl2lds16(const __hip_bfloat16* g, __hip_bfloat16* l) {
    __builtin_amdgcn_global_load_lds(
        (const __attribute__((address_space(1))) unsigned int*)(g),
        (__attribute__((address_space(3))) unsigned int*)(l),
        16, 0, 0);
}

__device__ __forceinline__ uint4 cvt8_bf16(const float4 a, const float4 b) {
    union { __hip_bfloat16 h[8]; uint4 u; } t;
    t.h[0] = __float2bfloat16(a.x); t.h[1] = __float2bfloat16(a.y);
    t.h[2] = __float2bfloat16(a.z); t.h[3] = __float2bfloat16(a.w);
    t.h[4] = __float2bfloat16(b.x); t.h[5] = __float2bfloat16(b.y);
    t.h[6] = __float2bfloat16(b.z); t.h[7] = __float2bfloat16(b.w);
    return t.u;
}

// ---------------------------------------------------------------------------
// prep (r6 structure): X cvt (3072 blks), W cvt (512 blks), mask ballot
// grid-strided: 2048 blks x 16 rounds x 256 thr = 8,388,608 = BB*LL*LL.
// Mask bits stored TRANSPOSED: mbitsT[(kw*BB + b)*LL + q] so attn's per-lane
// reads (consecutive q) are coalesced (4 cache lines/wave vs 32 scattered).
// ---------------------------------------------------------------------------
struct PrepArgs {
    const float* xsrc[3];
    __hip_bfloat16* xdst[3];
    const float* wsrc[4];
    __hip_bfloat16* wdst[4];
    const int* mask;
    unsigned long long* mbits;
};

__global__ __launch_bounds__(256) void prep(PrepArgs a) {
    const int blk = blockIdx.x;
    if (blk < 3072) {
        const int t = blk >> 10;
        const int i = ((blk & 1023) * 256 + threadIdx.x) * 8;
        const float* s = a.xsrc[t] + i;
        float4 f0 = *(const float4*)(s);
        float4 f1 = *(const float4*)(s + 4);
        *(uint4*)(a.xdst[t] + i) = cvt8_bf16(f0, f1);
    } else if (blk < 3584) {
        const int r = blk - 3072;
        const int t = r >> 7;
        const int i = ((r & 127) * 256 + threadIdx.x) * 8;
        const float* s = a.wsrc[t] + i;
        float4 f0 = *(const float4*)(s);
        float4 f1 = *(const float4*)(s + 4);
        *(uint4*)(a.wdst[t] + i) = cvt8_bf16(f0, f1);
    } else {
        const int mb = blk - 3584;   // 0..2047, 16 rounds each
        #pragma unroll
        for (int r = 0; r < 16; ++r) {
            const size_t idx = ((size_t)mb * 16 + r) * 256 + threadIdx.x;
            const int m = a.mask[idx];
            const unsigned long long w = __ballot(m != 0);
            if ((threadIdx.x & 63) == 0) {
                const unsigned int widx = (unsigned int)(idx >> 6); // (b*LL+q)*LW+kw
                const unsigned int kw = widx & (LW - 1);
                const unsigned int bq = widx >> 5;                  // b*LL + q
                const unsigned int b = bq >> 11, q = bq & 2047;
                a.mbits[((size_t)kw * BB + b) * LL + q] = w;
            }
        }
    }
}

// ---------------------------------------------------------------------------
// bf16 GEMM (r3/r6 geometry, best measured): tile 64(M) x 128(N), BK=64,
// 4 waves (each M64 x N32: 4x2 frags, 16 MFMA/iter). LDS double-buffered via
// global_load_lds w=16 into unpadded [buf][khalf][rows][32]. One barrier/iter.
// 768 blocks = 3 blocks/CU (48KB LDS) - balanced grid.
// z==0: q output with QSCALE folded.  z==2: writes V^T [B,H,D,L] DIRECTLY.
// ---------------------------------------------------------------------------
struct QKVArgs {
    const __hip_bfloat16* X[3];
    const __hip_bfloat16* W[3];
    const float* bias[3];
    __hip_bfloat16* O[3];   // O[2] = vtg (transposed layout)
};

__global__ __launch_bounds__(256) void gemm_qkv(QKVArgs p) {
    __shared__ __hip_bfloat16 As[2][2][64][32];    // 16KB
    __shared__ __hip_bfloat16 Bs[2][2][128][32];   // 32KB

    const int z = blockIdx.z;
    const __hip_bfloat16* __restrict__ X = p.X[z];
    const __hip_bfloat16* __restrict__ W = p.W[z];
    const float* __restrict__ bias = p.bias[z];
    __hip_bfloat16* __restrict__ O = p.O[z];

    const int tid = threadIdx.x;
    const int wave = tid >> 6, lane = tid & 63;
    const int l15 = lane & 15, quad = lane >> 4;
    const int wn = wave * 32;
    const int m0 = blockIdx.y * 64, n0 = blockIdx.x * 128;

    const int lr = lane >> 2;          // 0..15
    const int lc = (lane & 3) * 8;
    const __hip_bfloat16* Ax = X + (size_t)(m0 + wave * 16 + lr) * EE + lc;
    const __hip_bfloat16* Bx = W + (size_t)(n0 + wave * 32 + lr) * EE + lc;

    f32x4 acc[4][2] = {};

    #define STAGE_G(buf, k0)                                                   \
        gl2lds16(Ax + (k0),           &As[buf][0][wave * 16][0]);              \
        gl2lds16(Ax + (k0) + 32,      &As[buf][1][wave * 16][0]);              \
        gl2lds16(Bx + (k0),           &Bs[buf][0][wave * 32][0]);              \
        gl2lds16(Bx + (k0) + 32,      &Bs[buf][1][wave * 32][0]);              \
        gl2lds16(Bx + (k0) + 16 * EE,      &Bs[buf][0][wave * 32 + 16][0]);    \
        gl2lds16(Bx + (k0) + 16 * EE + 32, &Bs[buf][1][wave * 32 + 16][0]);

    STAGE_G(0, 0);
    __syncthreads();

    for (int kt = 0; kt < 8; ++kt) {
        const int cur = kt & 1;
        if (kt < 7) { STAGE_G(cur ^ 1, (kt + 1) * 64); }

        #pragma unroll
        for (int c = 0; c < 2; ++c) {
            bf16x8 af[4], bf2[2];
            #pragma unroll
            for (int i = 0; i < 4; ++i)
                af[i] = *(const bf16x8*)&As[cur][c][i * 16 + l15][quad * 8];
            #pragma unroll
            for (int j = 0; j < 2; ++j)
                bf2[j] = *(const bf16x8*)&Bs[cur][c][wn + j * 16 + l15][quad * 8];
            #pragma unroll
            for (int i = 0; i < 4; ++i)
                #pragma unroll
                for (int j = 0; j < 2; ++j)
                    acc[i][j] = MFMA16(af[i], bf2[j], acc[i][j]);
        }
        __syncthreads();
    }

    if (z == 2) {
        // V^T write: vtg[((b*HH+h)*DD+d)*LL + l], 4 consecutive l per store
        #pragma unroll
        for (int i = 0; i < 4; ++i)
            #pragma unroll
            for (int j = 0; j < 2; ++j) {
                const int n = n0 + wn + j * 16 + l15;
                const float bv = bias[n];
                const int h = n >> 6, d = n & 63;
                union { __hip_bfloat16 hh[4]; ushort4 v4; } pk;
                #pragma unroll
                for (int reg = 0; reg < 4; ++reg)
                    pk.hh[reg] = __float2bfloat16(acc[i][j][reg] + bv);
                const int m = m0 + i * 16 + quad * 4;   // 4 consecutive l
                const int bb = m >> 11, l = m & 2047;
                *(ushort4*)&O[(((size_t)bb * HH + h) * DD + d) * LL + l] = pk.v4;
            }
    } else {
        const float oscale = (z == 0) ? QSCALE : 1.0f;
        #pragma unroll
        for (int i = 0; i < 4; ++i)
            #pragma unroll
            for (int j = 0; j < 2; ++j) {
                const int n = n0 + wn + j * 16 + l15;
                const float bv = bias[n];
                #pragma unroll
                for (int reg = 0; reg < 4; ++reg) {
                    const int m = m0 + i * 16 + quad * 4 + reg;
                    O[(size_t)m * EE + n] = __float2bfloat16((acc[i][j][reg] + bv) * oscale);
                }
            }
    }
}

// ---------------------------------------------------------------------------
// gemm_out FUSED with combine (r6): A = (Op0 + Op1) * (1/(l0+l1)) converted
// to bf16 during reg-staging (T14). B (Wo) via global_load_lds. Tile 64x128,
// 4 waves, 256 blocks (1/CU) XCD-pinned flat. h = kt is uniform per k-tile.
// ---------------------------------------------------------------------------
__global__ __launch_bounds__(256) void gemm_out(
    const float* __restrict__ Op, const float* __restrict__ lp,
    const __hip_bfloat16* __restrict__ W, const float* __restrict__ bias,
    float* __restrict__ C) {
    __shared__ __hip_bfloat16 As[2][2][64][32];
    __shared__ __hip_bfloat16 Bs[2][2][128][32];

    // XCD-pinned decode: 256 blocks = 8 xcd x 8 m-panels x 4 n-tiles
    const int flat = blockIdx.x;
    const int cx = flat & 7;
    const int s = flat >> 3;               // 0..31
    const int xn = s & 3;
    const int ym = cx * 8 + (s >> 2);      // 0..63

    const int tid = threadIdx.x;
    const int wave = tid >> 6, lane = tid & 63;
    const int l15 = lane & 15, quad = lane >> 4;
    const int wn = wave * 32;
    const int m0 = ym * 64, n0 = xn * 128;

    const int lr = lane >> 2;
    const int lc = (lane & 3) * 8;
    const int mrow = m0 + wave * 16 + lr;
    const int bb = mrow >> 11, qq = mrow & 2047;
    const float* Ax0 = Op + (size_t)mrow * EE + lc;           // sp=0
    const float* Ax1 = Ax0 + (size_t)MM * EE;                 // sp=1
    const float* lq0 = lp + (size_t)bb * HH * LL + qq;        // [h*LL] indexes h
    const float* lq1 = lp + ((size_t)(BB + bb)) * HH * LL + qq;
    const __hip_bfloat16* Bx = W + (size_t)(n0 + wave * 32 + lr) * EE + lc;

    f32x4 acc[4][2] = {};

    float4 ar[8];     // [0..3]=Op0 (c0 lo/hi, c1 lo/hi), [4..7]=Op1
    float lsum;

    #define LOAD_A(k0)                                                         \
        lsum = lq0[(size_t)((k0) >> 6) * LL] + lq1[(size_t)((k0) >> 6) * LL];  \
        ar[0] = *(const float4*)(Ax0 + (k0));                                  \
        ar[1] = *(const float4*)(Ax0 + (k0) + 4);                              \
        ar[2] = *(const float4*)(Ax0 + (k0) + 32);                             \
        ar[3] = *(const float4*)(Ax0 + (k0) + 36);                             \
        ar[4] = *(const float4*)(Ax1 + (k0));                                  \
        ar[5] = *(const float4*)(Ax1 + (k0) + 4);                              \
        ar[6] = *(const float4*)(Ax1 + (k0) + 32);                             \
        ar[7] = *(const float4*)(Ax1 + (k0) + 36);

    #define WRITE_A(buf)                                                       \
        {                                                                      \
            const float linv = 1.f / lsum;                                     \
            float4 s0, s1;                                                     \
            s0.x = (ar[0].x + ar[4].x) * linv; s0.y = (ar[0].y + ar[4].y) * linv; \
            s0.z = (ar[0].z + ar[4].z) * linv; s0.w = (ar[0].w + ar[4].w) * linv; \
            s1.x = (ar[1].x + ar[5].x) * linv; s1.y = (ar[1].y + ar[5].y) * linv; \
            s1.z = (ar[1].z + ar[5].z) * linv; s1.w = (ar[1].w + ar[5].w) * linv; \
            *(uint4*)&As[buf][0][wave * 16 + lr][lc] = cvt8_bf16(s0, s1);      \
            s0.x = (ar[2].x + ar[6].x) * linv; s0.y = (ar[2].y + ar[6].y) * linv; \
            s0.z = (ar[2].z + ar[6].z) * linv; s0.w = (ar[2].w + ar[6].w) * linv; \
            s1.x = (ar[3].x + ar[7].x) * linv; s1.y = (ar[3].y + ar[7].y) * linv; \
            s1.z = (ar[3].z + ar[7].z) * linv; s1.w = (ar[3].w + ar[7].w) * linv; \
            *(uint4*)&As[buf][1][wave * 16 + lr][lc] = cvt8_bf16(s0, s1);      \
        }

    #define STAGE_B(buf, k0)                                                   \
        gl2lds16(Bx + (k0),                &Bs[buf][0][wave * 32][0]);         \
        gl2lds16(Bx + (k0) + 32,           &Bs[buf][1][wave * 32][0]);         \
        gl2lds16(Bx + (k0) + 16 * EE,      &Bs[buf][0][wave * 32 + 16][0]);    \
        gl2lds16(Bx + (k0) + 16 * EE + 32, &Bs[buf][1][wave * 32 + 16][0]);

    LOAD_A(0);
    STAGE_B(0, 0);
    WRITE_A(0);
    __syncthreads();

    for (int kt = 0; kt < 8; ++kt) {
        const int cur = kt & 1;
        if (kt < 7) { LOAD_A((kt + 1) * 64); STAGE_B(cur ^ 1, (kt + 1) * 64); }

        #pragma unroll
        for (int c = 0; c < 2; ++c) {
            bf16x8 af[4], bf2[2];
            #pragma unroll
            for (int i = 0; i < 4; ++i)
                af[i] = *(const bf16x8*)&As[cur][c][i * 16 + l15][quad * 8];
            #pragma unroll
            for (int j = 0; j < 2; ++j)
                bf2[j] = *(const bf16x8*)&Bs[cur][c][wn + j * 16 + l15][quad * 8];
            #pragma unroll
            for (int i = 0; i < 4; ++i)
                #pragma unroll
                for (int j = 0; j < 2; ++j)
                    acc[i][j] = MFMA16(af[i], bf2[j], acc[i][j]);
        }
        if (kt < 7) { WRITE_A(cur ^ 1); }
        __syncthreads();
    }

    #pragma unroll
    for (int i = 0; i < 4; ++i)
        #pragma unroll
        for (int j = 0; j < 2; ++j) {
            const int n = n0 + wn + j * 16 + l15;
            const float bv = bias[n];
            #pragma unroll
            for (int reg = 0; reg < 4; ++reg) {
                const int m = m0 + i * 16 + quad * 4 + reg;
                C[(size_t)m * EE + n] = acc[i][j][reg] + bv;
            }
        }
}

// ---------------------------------------------------------------------------
// Flash attention v4 (r3/r6 best) + coalesced transposed mask reads:
// 32x32x16 MFMA, 4 waves x 32 q-rows (q-tile 128), KV-split x2.
// Flat 512-block grid with XCD-PINNED decode. In-register softmax via
// swapped QK^T; P -> bf16 PV A-frags with packed cvt + v_permlane32_swap_b32
// (T12). s_setprio around MFMA (T5). LDS = K/V double-buffer (34.8 KB).
// ---------------------------------------------------------------------------
__global__ __launch_bounds__(256, 2) void attn_mfma(
    const __hip_bfloat16* __restrict__ Qb, const __hip_bfloat16* __restrict__ Kb,
    const __hip_bfloat16* __restrict__ vtg, const unsigned long long* __restrict__ mbits,
    float* __restrict__ Op, float* __restrict__ lp) {
    __shared__ __hip_bfloat16 Ks[2][64][68];
    __shared__ __hip_bfloat16 Vs[2][64][68];

    const int tid = threadIdx.x;
    const int wave = tid >> 6, lane = tid & 63;
    const int l31 = lane & 31, hi = lane >> 5;

    // XCD-pinned decode: flat -> (xcd c, group g=(b,h,sp), q-tile qx)
    const int flat = blockIdx.x;          // 0..511
    const int c = flat & 7;               // xcd (round-robin linear dispatch)
    const int i = flat >> 3;              // 0..63 slot within xcd
    const int gl = i >> 4;                // 0..3 local group
    const int qx = i & 15;                // q-tile
    const int g = c * 4 + gl;             // 0..31 global group
    const int sp = g & 1;
    const int rem = g >> 1;               // 0..15
    const int h = rem & 7;
    const int b = rem >> 3;
    const int q0 = qx * 128;
    const int qrow = q0 + wave * 32 + l31;   // this lane's q (S^T col / lrun owner)

    const int srow = tid >> 2, sc0 = (tid & 3) * 16;   // staging: row, col-quarter
    const int t0 = sp * NT;

    // Q B-fragments: lane = col q, k(=d) = kk*16 + hi*8 .. +7
    bf16x8 qf[4];
    {
        const __hip_bfloat16* qr = Qb + ((size_t)b * LL + qrow) * EE + h * DD + hi * 8;
        qf[0] = *(const bf16x8*)(qr);
        qf[1] = *(const bf16x8*)(qr + 16);
        qf[2] = *(const bf16x8*)(qr + 32);
        qf[3] = *(const bf16x8*)(qr + 48);
    }

    const __hip_bfloat16* kbase =
        Kb + ((size_t)b * LL + (size_t)t0 * 64 + srow) * EE + h * DD + sc0;
    const __hip_bfloat16* vbase =
        vtg + (((size_t)b * HH + h) * DD + srow) * LL + (size_t)t0 * 64 + sc0;
    // transposed mask: mbitsT[(kw*BB + b)*LL + q] -> coalesced across lanes
    const unsigned long long* mrow = mbits + ((size_t)t0 * BB + b) * LL + qrow;

    f32x16 o0 = {}, o1 = {};
    float lrun = 0.f;

    {   // prologue stage tile t0 (each thread: 32B of K, 32B of V)
        uint4 k0 = *(const uint4*)(kbase);
        uint4 k1 = *(const uint4*)(kbase + 8);
        uint4 v0 = *(const uint4*)(vbase);
        uint4 v1 = *(const uint4*)(vbase + 8);
        *(uint4*)&Ks[0][srow][sc0] = k0;
        *(uint4*)&Ks[0][srow][sc0 + 8] = k1;
        *(uint4*)&Vs[0][srow][sc0] = v0;
        *(uint4*)&Vs[0][srow][sc0 + 8] = v1;
    }
    unsigned long long mw_cur = mrow[0];
    __syncthreads();

    for (int t = 0; t < NT; ++t) {
        const int cur = t & 1, nxt = cur ^ 1;
        const bool more = (t + 1) < NT;

        // register prefetch for next tile (T14 async split)
        uint4 kn0, kn1, vn0, vn1;
        unsigned long long mw_n;
        if (more) {
            const __hip_bfloat16* kp = kbase + (size_t)(t + 1) * 64 * EE;
            const __hip_bfloat16* vp = vbase + (t + 1) * 64;
            kn0 = *(const uint4*)(kp);
            kn1 = *(const uint4*)(kp + 8);
            vn0 = *(const uint4*)(vp);
            vn1 = *(const uint4*)(vp + 8);
            mw_n = mrow[(size_t)(t + 1) * BB * LL];
        }

        // ---- S^T = K (Q*scale*log2e)^T : two 32-row k-tiles, contraction D=64
        f32x16 st0 = {}, st1 = {};
        __builtin_amdgcn_s_setprio(1);
        #pragma unroll
        for (int kk = 0; kk < 4; ++kk) {
            bf16x8 kf0 = *(const bf16x8*)&Ks[cur][l31][kk * 16 + hi * 8];
            bf16x8 kf1 = *(const bf16x8*)&Ks[cur][32 + l31][kk * 16 + hi * 8];
            st0 = MFMA32(kf0, qf[kk], st0);
            st1 = MFMA32(kf1, qf[kk], st1);
        }
        __builtin_amdgcn_s_setprio(0);

        // ---- in-register no-max softmax + pack to PV A-fragments ----
        // S^T reg r holds k_local = kt*32 + (r&3) + 8*(r>>2) + 4*hi, col q=l31
        const unsigned long long msh = mw_cur >> (4 * hi);
        const unsigned int m32a = (unsigned int)msh;
        const unsigned int m32b = (unsigned int)(msh >> 32);
        bf16x8 pa[4];
        #pragma unroll
        for (int kt = 0; kt < 2; ++kt) {
            const f32x16 stv = kt ? st1 : st0;
            const unsigned int mm = kt ? m32b : m32a;
            float p[16];
            #pragma unroll
            for (int r = 0; r < 16; ++r) {
                const int bit = (r & 3) + 8 * (r >> 2);
                const float e = EXP2(stv[r]);
                p[r] = ((mm >> bit) & 1u) ? e : 0.f;
            }
            lrun += (((p[0] + p[1]) + (p[2] + p[3])) + ((p[4] + p[5]) + (p[6] + p[7])))
                  + (((p[8] + p[9]) + (p[10] + p[11])) + ((p[12] + p[13]) + (p[14] + p[15])));
            unsigned int w[8];
            #pragma unroll
            for (int i2 = 0; i2 < 8; ++i2) {
                union { __hip_bfloat162 h2; unsigned int u; } cv;
                cv.h2 = __float22bfloat162_rn(make_float2(p[2 * i2], p[2 * i2 + 1]));
                w[i2] = cv.u;
            }
            // exchange halves: dst.row1 <-> src.row0 fills two A-frag words/swap
            asm volatile("v_permlane32_swap_b32 %0, %1" : "+v"(w[0]), "+v"(w[2]));
            asm volatile("v_permlane32_swap_b32 %0, %1" : "+v"(w[1]), "+v"(w[3]));
            asm volatile("v_permlane32_swap_b32 %0, %1" : "+v"(w[4]), "+v"(w[6]));
            asm volatile("v_permlane32_swap_b32 %0, %1" : "+v"(w[5]), "+v"(w[7]));
            union { unsigned int u[4]; bf16x8 v; } f0, f1;
            f0.u[0] = w[0]; f0.u[1] = w[1]; f0.u[2] = w[2]; f0.u[3] = w[3];
            f1.u[0] = w[4]; f1.u[1] = w[5]; f1.u[2] = w[6]; f1.u[3] = w[7];
            pa[kt * 2] = f0.v;       // k-window kt*32 + [0,16)
            pa[kt * 2 + 1] = f1.v;   // k-window kt*32 + [16,32)
        }

        // ---- O += P V : 2 d-tiles x 4 k-windows ----
        __builtin_amdgcn_s_setprio(1);
        #pragma unroll
        for (int wd = 0; wd < 4; ++wd) {
            bf16x8 vf0 = *(const bf16x8*)&Vs[cur][l31][wd * 16 + hi * 8];
            bf16x8 vf1 = *(const bf16x8*)&Vs[cur][32 + l31][wd * 16 + hi * 8];
            o0 = MFMA32(pa[wd], vf0, o0);
            o1 = MFMA32(pa[wd], vf1, o1);
        }
        __builtin_amdgcn_s_setprio(0);

        if (more) {
            *(uint4*)&Ks[nxt][srow][sc0] = kn0;
            *(uint4*)&Ks[nxt][srow][sc0 + 8] = kn1;
            *(uint4*)&Vs[nxt][srow][sc0] = vn0;
            *(uint4*)&Vs[nxt][srow][sc0 + 8] = vn1;
            mw_cur = mw_n;
        }
        __syncthreads();
    }

    // partial row-sum: lanes l and l^32 hold disjoint k-subsets of same q
    lrun += __shfl_xor(lrun, 32);
    if (hi == 0)
        lp[(((size_t)sp * BB + b) * HH + h) * LL + qrow] = lrun;

    // partial O (unnormalized, fp32): row q = (r&3)+8*(r>>2)+4*hi, col d = l31
    float* Ob = Op + (size_t)sp * MM * EE
              + ((size_t)b * LL + q0 + wave * 32) * EE + h * DD;
    #pragma unroll
    for (int r = 0; r < 16; ++r) {
        const int qr = (r & 3) + 8 * (r >> 2) + 4 * hi;
        Ob[(size_t)qr * EE + l31] = o0[r];
        Ob[(size_t)qr * EE + 32 + l31] = o1[r];
    }
}

// ---------------------------------------------------------------------------
extern "C" void kernel_launch(void* const* d_in, const int* in_sizes, int n_in,
                              void* d_out, int out_size, void* d_ws, size_t ws_size,
                              hipStream_t stream) {
    const float* values = (const float*)d_in[0];
    const float* keys   = (const float*)d_in[1];
    const float* query  = (const float*)d_in[2];
    const int*   mask   = (const int*)d_in[3];
    const float* Wv = (const float*)d_in[4];
    const float* bv = (const float*)d_in[5];
    const float* Wk = (const float*)d_in[6];
    const float* bk = (const float*)d_in[7];
    const float* Wq = (const float*)d_in[8];
    const float* bq = (const float*)d_in[9];
    const float* Wo = (const float*)d_in[10];
    const float* bo = (const float*)d_in[11];
    float* out = (float*)d_out;

    const size_t XS = (size_t)MM * EE * 2;           // 4 MB bf16 [4096,512]
    const size_t WS = (size_t)EE * EE * 2;           // 0.5 MB bf16 [512,512]
    const size_t MBSZ = (size_t)BB * LL * LL / 8;    // 1 MB mask bits
    const size_t OPSZ = (size_t)MM * EE * 4;         // 8 MB fp32 partial O
    char* w = (char*)d_ws;
    __hip_bfloat16* xq  = (__hip_bfloat16*)(w);
    __hip_bfloat16* xk  = (__hip_bfloat16*)(w + XS);
    __hip_bfloat16* xv  = (__hip_bfloat16*)(w + 2 * XS);
    __hip_bfloat16* qb  = (__hip_bfloat16*)(w + 3 * XS);
    __hip_bfloat16* kb  = (__hip_bfloat16*)(w + 4 * XS);
    __hip_bfloat16* vtg = (__hip_bfloat16*)(w + 5 * XS);
    __hip_bfloat16* wqb = (__hip_bfloat16*)(w + 7 * XS);
    __hip_bfloat16* wkb = (__hip_bfloat16*)(w + 7 * XS + WS);
    __hip_bfloat16* wvb = (__hip_bfloat16*)(w + 7 * XS + 2 * WS);
    __hip_bfloat16* wob = (__hip_bfloat16*)(w + 7 * XS + 3 * WS);
    unsigned long long* mbits = (unsigned long long*)(w + 7 * XS + 4 * WS);
    float* Op = (float*)(w + 7 * XS + 4 * WS + MBSZ);                 // 2 x 8 MB
    float* lp = (float*)(w + 7 * XS + 4 * WS + MBSZ + NSP * OPSZ);    // 256 KB

    PrepArgs pa;
    pa.xsrc[0] = query; pa.xsrc[1] = keys; pa.xsrc[2] = values;
    pa.xdst[0] = xq;    pa.xdst[1] = xk;   pa.xdst[2] = xv;
    pa.wsrc[0] = Wq; pa.wsrc[1] = Wk; pa.wsrc[2] = Wv; pa.wsrc[3] = Wo;
    pa.wdst[0] = wqb; pa.wdst[1] = wkb; pa.wdst[2] = wvb; pa.wdst[3] = wob;
    pa.mask = mask; pa.mbits = mbits;

    QKVArgs qa;
    qa.X[0] = xq;  qa.X[1] = xk;  qa.X[2] = xv;
    qa.W[0] = wqb; qa.W[1] = wkb; qa.W[2] = wvb;
    qa.bias[0] = bq; qa.bias[1] = bk; qa.bias[2] = bv;
    qa.O[0] = qb;  qa.O[1] = kb;  qa.O[2] = vtg;   // z==2 writes V^T directly

    prep<<<5632, 256, 0, stream>>>(pa);
    gemm_qkv<<<dim3(EE / 128, MM / 64, 3), 256, 0, stream>>>(qa);
    // flat 512-block grid, XCD-pinned decode inside the kernel
    attn_mfma<<<dim3(512, 1, 1), 256, 0, stream>>>(qb, kb, vtg, mbits, Op, lp);
    // fused combine + output GEMM (256 blocks, XCD-pinned)
    gemm_out<<<dim3(256, 1, 1), 256, 0, stream>>>(Op, lp, wob, bo, out);
}

// Round 9
// 176.587 us; speedup vs baseline: 1.0320x; 1.0320x over previous
//
#include <hip/hip_runtime.h>
#include <hip/hip_bf16.h>
#include <math.h>

#define BB 2
#define LL 2048
#define EE 512
#define HH 8
#define DD 64
#define MM (BB * LL)   // 4096
#define LW (LL / 64)   // 32 mask words per row
#define NSP 2          // KV splits
#define KVB 128        // kv rows per attn iteration
#define NTI ((LL / NSP) / KVB)   // 8 iterations per split
#define NTW (LW / NSP)           // 16 mask words per split

typedef short bf16x8 __attribute__((ext_vector_type(8)));   // 8 bf16 = 4 VGPRs
typedef float f32x4 __attribute__((ext_vector_type(4)));
typedef float f32x16 __attribute__((ext_vector_type(16)));

#define MFMA16(a, b, c) __builtin_amdgcn_mfma_f32_16x16x32_bf16((a), (b), (c), 0, 0, 0)
#define MFMA32(a, b, c) __builtin_amdgcn_mfma_f32_32x32x16_bf16((a), (b), (c), 0, 0, 0)

#if __has_builtin(__builtin_amdgcn_exp2f)
#define EXP2(x) __builtin_amdgcn_exp2f(x)
#else
#define EXP2(x) exp2f(x)
#endif

// q-scale with log2(e) folded: (1/sqrt(512)) * log2(e)
#define QSCALE 0.0637587146f

// async global->LDS, 16B per lane; LDS dest = wave-uniform base + lane*16B
__device__ __forceinline__ void gl2lds16(const __hip_bfloat16* g, __hip_bfloat16* l) {
    __builtin_amdgcn_global_load_lds(
        (const __attribute__((address_space(1))) unsigned int*)(g),
        (__attribute__((address_space(3))) unsigned int*)(l),
        16, 0, 0);
}

__device__ __forceinline__ uint4 cvt8_bf16(const float4 a, const float4 b) {
    union { __hip_bfloat16 h[8]; uint4 u; } t;
    t.h[0] = __float2bfloat16(a.x); t.h[1] = __float2bfloat16(a.y);
    t.h[2] = __float2bfloat16(a.z); t.h[3] = __float2bfloat16(a.w);
    t.h[4] = __float2bfloat16(b.x); t.h[5] = __float2bfloat16(b.y);
    t.h[6] = __float2bfloat16(b.z); t.h[7] = __float2bfloat16(b.w);
    return t.u;
}

// ---------------------------------------------------------------------------
// prep (r6): X cvt (3072 blks), W cvt (512 blks), mask ballot grid-strided:
// 2048 blks x 16 rounds x 256 thr = 8,388,608 = BB*LL*LL exactly.
// mbits layout: [(b*LL+q)*LW + kw] (r6 original, coalesced stores).
// ---------------------------------------------------------------------------
struct PrepArgs {
    const float* xsrc[3];
    __hip_bfloat16* xdst[3];
    const float* wsrc[4];
    __hip_bfloat16* wdst[4];
    const int* mask;
    unsigned long long* mbits;
};

__global__ __launch_bounds__(256) void prep(PrepArgs a) {
    const int blk = blockIdx.x;
    if (blk < 3072) {
        const int t = blk >> 10;
        const int i = ((blk & 1023) * 256 + threadIdx.x) * 8;
        const float* s = a.xsrc[t] + i;
        float4 f0 = *(const float4*)(s);
        float4 f1 = *(const float4*)(s + 4);
        *(uint4*)(a.xdst[t] + i) = cvt8_bf16(f0, f1);
    } else if (blk < 3584) {
        const int r = blk - 3072;
        const int t = r >> 7;
        const int i = ((r & 127) * 256 + threadIdx.x) * 8;
        const float* s = a.wsrc[t] + i;
        float4 f0 = *(const float4*)(s);
        float4 f1 = *(const float4*)(s + 4);
        *(uint4*)(a.wdst[t] + i) = cvt8_bf16(f0, f1);
    } else {
        const int mb = blk - 3584;   // 0..2047, 16 rounds each
        #pragma unroll
        for (int r = 0; r < 16; ++r) {
            const size_t idx = ((size_t)mb * 16 + r) * 256 + threadIdx.x;
            const int m = a.mask[idx];
            const unsigned long long w = __ballot(m != 0);
            if ((threadIdx.x & 63) == 0) a.mbits[idx >> 6] = w;
        }
    }
}

// ---------------------------------------------------------------------------
// bf16 GEMM (r3/r6 geometry, best measured): tile 64(M) x 128(N), BK=64,
// 4 waves (each M64 x N32: 4x2 frags, 16 MFMA/iter). LDS double-buffered via
// global_load_lds w=16 into unpadded [buf][khalf][rows][32]. One barrier/iter.
// 768 blocks = 3 blocks/CU (48KB LDS) - balanced grid.
// z==0: q output with QSCALE folded.  z==2: writes V^T [B,H,D,L] DIRECTLY.
// ---------------------------------------------------------------------------
struct QKVArgs {
    const __hip_bfloat16* X[3];
    const __hip_bfloat16* W[3];
    const float* bias[3];
    __hip_bfloat16* O[3];   // O[2] = vtg (transposed layout)
};

__global__ __launch_bounds__(256) void gemm_qkv(QKVArgs p) {
    __shared__ __hip_bfloat16 As[2][2][64][32];    // 16KB
    __shared__ __hip_bfloat16 Bs[2][2][128][32];   // 32KB

    const int z = blockIdx.z;
    const __hip_bfloat16* __restrict__ X = p.X[z];
    const __hip_bfloat16* __restrict__ W = p.W[z];
    const float* __restrict__ bias = p.bias[z];
    __hip_bfloat16* __restrict__ O = p.O[z];

    const int tid = threadIdx.x;
    const int wave = tid >> 6, lane = tid & 63;
    const int l15 = lane & 15, quad = lane >> 4;
    const int wn = wave * 32;
    const int m0 = blockIdx.y * 64, n0 = blockIdx.x * 128;

    const int lr = lane >> 2;          // 0..15
    const int lc = (lane & 3) * 8;
    const __hip_bfloat16* Ax = X + (size_t)(m0 + wave * 16 + lr) * EE + lc;
    const __hip_bfloat16* Bx = W + (size_t)(n0 + wave * 32 + lr) * EE + lc;

    f32x4 acc[4][2] = {};

    #define STAGE_G(buf, k0)                                                   \
        gl2lds16(Ax + (k0),           &As[buf][0][wave * 16][0]);              \
        gl2lds16(Ax + (k0) + 32,      &As[buf][1][wave * 16][0]);              \
        gl2lds16(Bx + (k0),           &Bs[buf][0][wave * 32][0]);              \
        gl2lds16(Bx + (k0) + 32,      &Bs[buf][1][wave * 32][0]);              \
        gl2lds16(Bx + (k0) + 16 * EE,      &Bs[buf][0][wave * 32 + 16][0]);    \
        gl2lds16(Bx + (k0) + 16 * EE + 32, &Bs[buf][1][wave * 32 + 16][0]);

    STAGE_G(0, 0);
    __syncthreads();

    for (int kt = 0; kt < 8; ++kt) {
        const int cur = kt & 1;
        if (kt < 7) { STAGE_G(cur ^ 1, (kt + 1) * 64); }

        #pragma unroll
        for (int c = 0; c < 2; ++c) {
            bf16x8 af[4], bf2[2];
            #pragma unroll
            for (int i = 0; i < 4; ++i)
                af[i] = *(const bf16x8*)&As[cur][c][i * 16 + l15][quad * 8];
            #pragma unroll
            for (int j = 0; j < 2; ++j)
                bf2[j] = *(const bf16x8*)&Bs[cur][c][wn + j * 16 + l15][quad * 8];
            #pragma unroll
            for (int i = 0; i < 4; ++i)
                #pragma unroll
                for (int j = 0; j < 2; ++j)
                    acc[i][j] = MFMA16(af[i], bf2[j], acc[i][j]);
        }
        __syncthreads();
    }

    if (z == 2) {
        // V^T write: vtg[((b*HH+h)*DD+d)*LL + l], 4 consecutive l per store
        #pragma unroll
        for (int i = 0; i < 4; ++i)
            #pragma unroll
            for (int j = 0; j < 2; ++j) {
                const int n = n0 + wn + j * 16 + l15;
                const float bv = bias[n];
                const int h = n >> 6, d = n & 63;
                union { __hip_bfloat16 hh[4]; ushort4 v4; } pk;
                #pragma unroll
                for (int reg = 0; reg < 4; ++reg)
                    pk.hh[reg] = __float2bfloat16(acc[i][j][reg] + bv);
                const int m = m0 + i * 16 + quad * 4;   // 4 consecutive l
                const int bb = m >> 11, l = m & 2047;
                *(ushort4*)&O[(((size_t)bb * HH + h) * DD + d) * LL + l] = pk.v4;
            }
    } else {
        const float oscale = (z == 0) ? QSCALE : 1.0f;
        #pragma unroll
        for (int i = 0; i < 4; ++i)
            #pragma unroll
            for (int j = 0; j < 2; ++j) {
                const int n = n0 + wn + j * 16 + l15;
                const float bv = bias[n];
                #pragma unroll
                for (int reg = 0; reg < 4; ++reg) {
                    const int m = m0 + i * 16 + quad * 4 + reg;
                    O[(size_t)m * EE + n] = __float2bfloat16((acc[i][j][reg] + bv) * oscale);
                }
            }
    }
}

// ---------------------------------------------------------------------------
// gemm_out FUSED with combine (r6): A = (Op0 + Op1) * (1/(l0+l1)) converted
// to bf16 during reg-staging (T14). B (Wo) via global_load_lds. Tile 64x128,
// 4 waves, 256 blocks (1/CU) XCD-pinned flat. h = kt is uniform per k-tile.
// ---------------------------------------------------------------------------
__global__ __launch_bounds__(256) void gemm_out(
    const float* __restrict__ Op, const float* __restrict__ lp,
    const __hip_bfloat16* __restrict__ W, const float* __restrict__ bias,
    float* __restrict__ C) {
    __shared__ __hip_bfloat16 As[2][2][64][32];
    __shared__ __hip_bfloat16 Bs[2][2][128][32];

    // XCD-pinned decode: 256 blocks = 8 xcd x 8 m-panels x 4 n-tiles
    const int flat = blockIdx.x;
    const int cx = flat & 7;
    const int s = flat >> 3;               // 0..31
    const int xn = s & 3;
    const int ym = cx * 8 + (s >> 2);      // 0..63

    const int tid = threadIdx.x;
    const int wave = tid >> 6, lane = tid & 63;
    const int l15 = lane & 15, quad = lane >> 4;
    const int wn = wave * 32;
    const int m0 = ym * 64, n0 = xn * 128;

    const int lr = lane >> 2;
    const int lc = (lane & 3) * 8;
    const int mrow = m0 + wave * 16 + lr;
    const int bb = mrow >> 11, qq = mrow & 2047;
    const float* Ax0 = Op + (size_t)mrow * EE + lc;           // sp=0
    const float* Ax1 = Ax0 + (size_t)MM * EE;                 // sp=1
    const float* lq0 = lp + (size_t)bb * HH * LL + qq;        // [h*LL] indexes h
    const float* lq1 = lp + ((size_t)(BB + bb)) * HH * LL + qq;
    const __hip_bfloat16* Bx = W + (size_t)(n0 + wave * 32 + lr) * EE + lc;

    f32x4 acc[4][2] = {};

    float4 ar[8];     // [0..3]=Op0 (c0 lo/hi, c1 lo/hi), [4..7]=Op1
    float lsum;

    #define LOAD_A(k0)                                                         \
        lsum = lq0[(size_t)((k0) >> 6) * LL] + lq1[(size_t)((k0) >> 6) * LL];  \
        ar[0] = *(const float4*)(Ax0 + (k0));                                  \
        ar[1] = *(const float4*)(Ax0 + (k0) + 4);                              \
        ar[2] = *(const float4*)(Ax0 + (k0) + 32);                             \
        ar[3] = *(const float4*)(Ax0 + (k0) + 36);                             \
        ar[4] = *(const float4*)(Ax1 + (k0));                                  \
        ar[5] = *(const float4*)(Ax1 + (k0) + 4);                              \
        ar[6] = *(const float4*)(Ax1 + (k0) + 32);                             \
        ar[7] = *(const float4*)(Ax1 + (k0) + 36);

    #define WRITE_A(buf)                                                       \
        {                                                                      \
            const float linv = 1.f / lsum;                                     \
            float4 s0, s1;                                                     \
            s0.x = (ar[0].x + ar[4].x) * linv; s0.y = (ar[0].y + ar[4].y) * linv; \
            s0.z = (ar[0].z + ar[4].z) * linv; s0.w = (ar[0].w + ar[4].w) * linv; \
            s1.x = (ar[1].x + ar[5].x) * linv; s1.y = (ar[1].y + ar[5].y) * linv; \
            s1.z = (ar[1].z + ar[5].z) * linv; s1.w = (ar[1].w + ar[5].w) * linv; \
            *(uint4*)&As[buf][0][wave * 16 + lr][lc] = cvt8_bf16(s0, s1);      \
            s0.x = (ar[2].x + ar[6].x) * linv; s0.y = (ar[2].y + ar[6].y) * linv; \
            s0.z = (ar[2].z + ar[6].z) * linv; s0.w = (ar[2].w + ar[6].w) * linv; \
            s1.x = (ar[3].x + ar[7].x) * linv; s1.y = (ar[3].y + ar[7].y) * linv; \
            s1.z = (ar[3].z + ar[7].z) * linv; s1.w = (ar[3].w + ar[7].w) * linv; \
            *(uint4*)&As[buf][1][wave * 16 + lr][lc] = cvt8_bf16(s0, s1);      \
        }

    #define STAGE_B(buf, k0)                                                   \
        gl2lds16(Bx + (k0),                &Bs[buf][0][wave * 32][0]);         \
        gl2lds16(Bx + (k0) + 32,           &Bs[buf][1][wave * 32][0]);         \
        gl2lds16(Bx + (k0) + 16 * EE,      &Bs[buf][0][wave * 32 + 16][0]);    \
        gl2lds16(Bx + (k0) + 16 * EE + 32, &Bs[buf][1][wave * 32 + 16][0]);

    LOAD_A(0);
    STAGE_B(0, 0);
    WRITE_A(0);
    __syncthreads();

    for (int kt = 0; kt < 8; ++kt) {
        const int cur = kt & 1;
        if (kt < 7) { LOAD_A((kt + 1) * 64); STAGE_B(cur ^ 1, (kt + 1) * 64); }

        #pragma unroll
        for (int c = 0; c < 2; ++c) {
            bf16x8 af[4], bf2[2];
            #pragma unroll
            for (int i = 0; i < 4; ++i)
                af[i] = *(const bf16x8*)&As[cur][c][i * 16 + l15][quad * 8];
            #pragma unroll
            for (int j = 0; j < 2; ++j)
                bf2[j] = *(const bf16x8*)&Bs[cur][c][wn + j * 16 + l15][quad * 8];
            #pragma unroll
            for (int i = 0; i < 4; ++i)
                #pragma unroll
                for (int j = 0; j < 2; ++j)
                    acc[i][j] = MFMA16(af[i], bf2[j], acc[i][j]);
        }
        if (kt < 7) { WRITE_A(cur ^ 1); }
        __syncthreads();
    }

    #pragma unroll
    for (int i = 0; i < 4; ++i)
        #pragma unroll
        for (int j = 0; j < 2; ++j) {
            const int n = n0 + wn + j * 16 + l15;
            const float bv = bias[n];
            #pragma unroll
            for (int reg = 0; reg < 4; ++reg) {
                const int m = m0 + i * 16 + quad * 4 + reg;
                C[(size_t)m * EE + n] = acc[i][j][reg] + bv;
            }
        }
}

// ---------------------------------------------------------------------------
// Flash attention v6: v4 structure with KVBLK=128 (two sequential 64-row
// halves per iteration -> S^T stays 32 VGPRs). Barriers/block 16 -> 8;
// mask words load as one aligned ulonglong2 per iter. K prefetch issued at
// iter top, V prefetch after half-0 softmax (staggered to cap VGPR < 128).
// 32x32x16 MFMA, 4 waves x 32 q-rows, KV-split x2, XCD-pinned flat grid.
// In-register softmax via swapped QK^T; P -> bf16 via packed cvt +
// v_permlane32_swap_b32 (T12). s_setprio around MFMA (T5). LDS 67 KB.
// ---------------------------------------------------------------------------
__global__ __launch_bounds__(256, 2) void attn_mfma(
    const __hip_bfloat16* __restrict__ Qb, const __hip_bfloat16* __restrict__ Kb,
    const __hip_bfloat16* __restrict__ vtg, const unsigned long long* __restrict__ mbits,
    float* __restrict__ Op, float* __restrict__ lp) {
    __shared__ __hip_bfloat16 Ks[2][128][68];   // [l][d]  34.0 KB
    __shared__ __hip_bfloat16 Vs[2][64][132];   // [d][l]  33.0 KB

    const int tid = threadIdx.x;
    const int wave = tid >> 6, lane = tid & 63;
    const int l31 = lane & 31, hi = lane >> 5;

    // XCD-pinned decode: flat -> (xcd c, group g=(b,h,sp), q-tile qx)
    const int flat = blockIdx.x;          // 0..511
    const int c = flat & 7;               // xcd (round-robin linear dispatch)
    const int i = flat >> 3;              // 0..63 slot within xcd
    const int gl = i >> 4;                // 0..3 local group
    const int qx = i & 15;                // q-tile
    const int g = c * 4 + gl;             // 0..31 global group
    const int sp = g & 1;
    const int rem = g >> 1;               // 0..15
    const int h = rem & 7;
    const int b = rem >> 3;
    const int q0 = qx * 128;
    const int qrow = q0 + wave * 32 + l31;   // this lane's q (S^T col / lrun owner)

    const int kv0 = sp * (LL / NSP);

    // staging decomposition: K = 128 rows x 64 d (64B/thread);
    //                        V = 64 d-rows x 128 l (64B/thread)
    const int srk = tid >> 1, sck = (tid & 1) * 32;
    const int srv = tid >> 2, scv = (tid & 3) * 32;

    // Q B-fragments: lane = col q, k(=d) = kk*16 + hi*8 .. +7
    bf16x8 qf[4];
    {
        const __hip_bfloat16* qr = Qb + ((size_t)b * LL + qrow) * EE + h * DD + hi * 8;
        qf[0] = *(const bf16x8*)(qr);
        qf[1] = *(const bf16x8*)(qr + 16);
        qf[2] = *(const bf16x8*)(qr + 32);
        qf[3] = *(const bf16x8*)(qr + 48);
    }

    const __hip_bfloat16* kbase =
        Kb + ((size_t)b * LL + kv0 + srk) * EE + h * DD + sck;
    const __hip_bfloat16* vbase =
        vtg + (((size_t)b * HH + h) * DD + srv) * LL + kv0 + scv;
    const unsigned long long* mroww = mbits + ((size_t)b * LL + qrow) * LW + sp * NTW;

    f32x16 o0 = {}, o1 = {};
    float lrun = 0.f;

    {   // prologue stage tile 0 (each thread: 64B of K, 64B of V)
        uint4 k0 = *(const uint4*)(kbase);
        uint4 k1 = *(const uint4*)(kbase + 8);
        uint4 k2 = *(const uint4*)(kbase + 16);
        uint4 k3 = *(const uint4*)(kbase + 24);
        uint4 v0 = *(const uint4*)(vbase);
        uint4 v1 = *(const uint4*)(vbase + 8);
        uint4 v2 = *(const uint4*)(vbase + 16);
        uint4 v3 = *(const uint4*)(vbase + 24);
        *(uint4*)&Ks[0][srk][sck] = k0;
        *(uint4*)&Ks[0][srk][sck + 8] = k1;
        *(uint4*)&Ks[0][srk][sck + 16] = k2;
        *(uint4*)&Ks[0][srk][sck + 24] = k3;
        *(uint4*)&Vs[0][srv][scv] = v0;
        *(uint4*)&Vs[0][srv][scv + 8] = v1;
        *(uint4*)&Vs[0][srv][scv + 16] = v2;
        *(uint4*)&Vs[0][srv][scv + 24] = v3;
    }
    ulonglong2 mwc = *(const ulonglong2*)(mroww);
    __syncthreads();

    // one 64-row half: QK^T (rows RB..RB+63) + softmax(MW) + PV (l RB..RB+63)
    #define HALF(cur, RB, MW)                                                      \
    {                                                                              \
        f32x16 st0 = {}, st1 = {};                                                 \
        __builtin_amdgcn_s_setprio(1);                                             \
        _Pragma("unroll")                                                          \
        for (int kk = 0; kk < 4; ++kk) {                                           \
            bf16x8 kf0 = *(const bf16x8*)&Ks[cur][(RB) + l31][kk * 16 + hi * 8];   \
            bf16x8 kf1 = *(const bf16x8*)&Ks[cur][(RB) + 32 + l31][kk * 16 + hi * 8]; \
            st0 = MFMA32(kf0, qf[kk], st0);                                        \
            st1 = MFMA32(kf1, qf[kk], st1);                                        \
        }                                                                          \
        __builtin_amdgcn_s_setprio(0);                                             \
        const unsigned long long msh = (MW) >> (4 * hi);                           \
        const unsigned int m32a = (unsigned int)msh;                               \
        const unsigned int m32b = (unsigned int)(msh >> 32);                       \
        bf16x8 pa[4];                                                              \
        _Pragma("unroll")                                                          \
        for (int kt = 0; kt < 2; ++kt) {                                           \
            const f32x16 stv = kt ? st1 : st0;                                     \
            const unsigned int mm = kt ? m32b : m32a;                              \
            float p[16];                                                           \
            _Pragma("unroll")                                                      \
            for (int r = 0; r < 16; ++r) {                                         \
                const int bit = (r & 3) + 8 * (r >> 2);                            \
                const float e = EXP2(stv[r]);                                      \
                p[r] = ((mm >> bit) & 1u) ? e : 0.f;                               \
            }                                                                      \
            lrun += (((p[0]+p[1])+(p[2]+p[3]))+((p[4]+p[5])+(p[6]+p[7])))          \
                  + (((p[8]+p[9])+(p[10]+p[11]))+((p[12]+p[13])+(p[14]+p[15])));   \
            unsigned int w[8];                                                     \
            _Pragma("unroll")                                                      \
            for (int i2 = 0; i2 < 8; ++i2) {                                       \
                union { __hip_bfloat162 h2; unsigned int u; } cv;                  \
                cv.h2 = __float22bfloat162_rn(make_float2(p[2*i2], p[2*i2+1]));    \
                w[i2] = cv.u;                                                      \
            }                                                                      \
            asm volatile("v_permlane32_swap_b32 %0, %1" : "+v"(w[0]), "+v"(w[2])); \
            asm volatile("v_permlane32_swap_b32 %0, %1" : "+v"(w[1]), "+v"(w[3])); \
            asm volatile("v_permlane32_swap_b32 %0, %1" : "+v"(w[4]), "+v"(w[6])); \
            asm volatile("v_permlane32_swap_b32 %0, %1" : "+v"(w[5]), "+v"(w[7])); \
            union { unsigned int u[4]; bf16x8 v; } f0, f1;                         \
            f0.u[0] = w[0]; f0.u[1] = w[1]; f0.u[2] = w[2]; f0.u[3] = w[3];        \
            f1.u[0] = w[4]; f1.u[1] = w[5]; f1.u[2] = w[6]; f1.u[3] = w[7];        \
            pa[kt * 2] = f0.v;                                                     \
            pa[kt * 2 + 1] = f1.v;                                                 \
        }                                                                          \
        __builtin_amdgcn_s_setprio(1);                                             \
        _Pragma("unroll")                                                          \
        for (int wd = 0; wd < 4; ++wd) {                                           \
            bf16x8 vf0 = *(const bf16x8*)&Vs[cur][l31][(RB) + wd * 16 + hi * 8];   \
            bf16x8 vf1 = *(const bf16x8*)&Vs[cur][32 + l31][(RB) + wd * 16 + hi * 8]; \
            o0 = MFMA32(pa[wd], vf0, o0);                                          \
            o1 = MFMA32(pa[wd], vf1, o1);                                          \
        }                                                                          \
        __builtin_amdgcn_s_setprio(0);                                             \
    }

    for (int t = 0; t < NTI; ++t) {
        const int cur = t & 1, nxt = cur ^ 1;
        const bool more = (t + 1) < NTI;

        // K + mask prefetch issue (lands during half-0 compute)
        uint4 kn0, kn1, kn2, kn3;
        ulonglong2 mwn;
        if (more) {
            const __hip_bfloat16* kp = kbase + (size_t)(t + 1) * KVB * EE;
            kn0 = *(const uint4*)(kp);
            kn1 = *(const uint4*)(kp + 8);
            kn2 = *(const uint4*)(kp + 16);
            kn3 = *(const uint4*)(kp + 24);
            mwn = *(const ulonglong2*)(mroww + (size_t)(t + 1) * 2);
        }

        HALF(cur, 0, mwc.x);

        // V prefetch issue (lands during half-1 compute)
        uint4 vn0, vn1, vn2, vn3;
        if (more) {
            const __hip_bfloat16* vp = vbase + (size_t)(t + 1) * KVB;
            vn0 = *(const uint4*)(vp);
            vn1 = *(const uint4*)(vp + 8);
            vn2 = *(const uint4*)(vp + 16);
            vn3 = *(const uint4*)(vp + 24);
        }

        HALF(cur, 64, mwc.y);

        if (more) {
            *(uint4*)&Ks[nxt][srk][sck] = kn0;
            *(uint4*)&Ks[nxt][srk][sck + 8] = kn1;
            *(uint4*)&Ks[nxt][srk][sck + 16] = kn2;
            *(uint4*)&Ks[nxt][srk][sck + 24] = kn3;
            *(uint4*)&Vs[nxt][srv][scv] = vn0;
            *(uint4*)&Vs[nxt][srv][scv + 8] = vn1;
            *(uint4*)&Vs[nxt][srv][scv + 16] = vn2;
            *(uint4*)&Vs[nxt][srv][scv + 24] = vn3;
            mwc = mwn;
        }
        __syncthreads();
    }

    // partial row-sum: lanes l and l^32 hold disjoint k-subsets of same q
    lrun += __shfl_xor(lrun, 32);
    if (hi == 0)
        lp[(((size_t)sp * BB + b) * HH + h) * LL + qrow] = lrun;

    // partial O (unnormalized, fp32): row q = (r&3)+8*(r>>2)+4*hi, col d = l31
    float* Ob = Op + (size_t)sp * MM * EE
              + ((size_t)b * LL + q0 + wave * 32) * EE + h * DD;
    #pragma unroll
    for (int r = 0; r < 16; ++r) {
        const int qr = (r & 3) + 8 * (r >> 2) + 4 * hi;
        Ob[(size_t)qr * EE + l31] = o0[r];
        Ob[(size_t)qr * EE + 32 + l31] = o1[r];
    }
}

// ---------------------------------------------------------------------------
extern "C" void kernel_launch(void* const* d_in, const int* in_sizes, int n_in,
                              void* d_out, int out_size, void* d_ws, size_t ws_size,
                              hipStream_t stream) {
    const float* values = (const float*)d_in[0];
    const float* keys   = (const float*)d_in[1];
    const float* query  = (const float*)d_in[2];
    const int*   mask   = (const int*)d_in[3];
    const float* Wv = (const float*)d_in[4];
    const float* bv = (const float*)d_in[5];
    const float* Wk = (const float*)d_in[6];
    const float* bk = (const float*)d_in[7];
    const float* Wq = (const float*)d_in[8];
    const float* bq = (const float*)d_in[9];
    const float* Wo = (const float*)d_in[10];
    const float* bo = (const float*)d_in[11];
    float* out = (float*)d_out;

    const size_t XS = (size_t)MM * EE * 2;           // 4 MB bf16 [4096,512]
    const size_t WS = (size_t)EE * EE * 2;           // 0.5 MB bf16 [512,512]
    const size_t MBSZ = (size_t)BB * LL * LL / 8;    // 1 MB mask bits
    const size_t OPSZ = (size_t)MM * EE * 4;         // 8 MB fp32 partial O
    char* w = (char*)d_ws;
    __hip_bfloat16* xq  = (__hip_bfloat16*)(w);
    __hip_bfloat16* xk  = (__hip_bfloat16*)(w + XS);
    __hip_bfloat16* xv  = (__hip_bfloat16*)(w + 2 * XS);
    __hip_bfloat16* qb  = (__hip_bfloat16*)(w + 3 * XS);
    __hip_bfloat16* kb  = (__hip_bfloat16*)(w + 4 * XS);
    __hip_bfloat16* vtg = (__hip_bfloat16*)(w + 5 * XS);
    __hip_bfloat16* wqb = (__hip_bfloat16*)(w + 7 * XS);
    __hip_bfloat16* wkb = (__hip_bfloat16*)(w + 7 * XS + WS);
    __hip_bfloat16* wvb = (__hip_bfloat16*)(w + 7 * XS + 2 * WS);
    __hip_bfloat16* wob = (__hip_bfloat16*)(w + 7 * XS + 3 * WS);
    unsigned long long* mbits = (unsigned long long*)(w + 7 * XS + 4 * WS);
    float* Op = (float*)(w + 7 * XS + 4 * WS + MBSZ);                 // 2 x 8 MB
    float* lp = (float*)(w + 7 * XS + 4 * WS + MBSZ + NSP * OPSZ);    // 256 KB

    PrepArgs pa;
    pa.xsrc[0] = query; pa.xsrc[1] = keys; pa.xsrc[2] = values;
    pa.xdst[0] = xq;    pa.xdst[1] = xk;   pa.xdst[2] = xv;
    pa.wsrc[0] = Wq; pa.wsrc[1] = Wk; pa.wsrc[2] = Wv; pa.wsrc[3] = Wo;
    pa.wdst[0] = wqb; pa.wdst[1] = wkb; pa.wdst[2] = wvb; pa.wdst[3] = wob;
    pa.mask = mask; pa.mbits = mbits;

    QKVArgs qa;
    qa.X[0] = xq;  qa.X[1] = xk;  qa.X[2] = xv;
    qa.W[0] = wqb; qa.W[1] = wkb; qa.W[2] = wvb;
    qa.bias[0] = bq; qa.bias[1] = bk; qa.bias[2] = bv;
    qa.O[0] = qb;  qa.O[1] = kb;  qa.O[2] = vtg;   // z==2 writes V^T directly

    prep<<<5632, 256, 0, stream>>>(pa);
    gemm_qkv<<<dim3(EE / 128, MM / 64, 3), 256, 0, stream>>>(qa);
    // flat 512-block grid, XCD-pinned decode inside the kernel
    attn_mfma<<<dim3(512, 1, 1), 256, 0, stream>>>(qb, kb, vtg, mbits, Op, lp);
    // fused combine + output GEMM (256 blocks, XCD-pinned)
    gemm_out<<<dim3(256, 1, 1), 256, 0, stream>>>(Op, lp, wob, bo, out);
}